// Round 1
// baseline (36.596 us; speedup 1.0000x reference)
//
#include <hip/hip_runtime.h>

#define BB 16384
#define LL 200
#define DD 100
#define VV 100000

// Kernel 1: rowdot[v] = sum_d E[v,d] * w[d]. One wave (64 lanes) per row.
// Lanes read 100 contiguous floats (400 B) -> fully coalesced.
__global__ __launch_bounds__(256) void rowdot_kernel(const float* __restrict__ E,
                                                     const float* __restrict__ w,
                                                     float* __restrict__ rowdot) {
    int wave = (blockIdx.x * blockDim.x + threadIdx.x) >> 6;
    int lane = threadIdx.x & 63;
    if (wave >= VV) return;
    const float* row = E + (size_t)wave * DD;
    float s = 0.0f;
    if (lane < DD) s = row[lane] * w[lane];
    int d2 = lane + 64;
    if (d2 < DD) s += row[d2] * w[d2];
    #pragma unroll
    for (int off = 32; off > 0; off >>= 1)
        s += __shfl_down(s, off, 64);
    if (lane == 0) rowdot[wave] = s;
}

// Kernel 2: out[b] = (1/L) * sum_l rowdot[idx[b,l]]. One wave per batch row.
// Index reads coalesced (lane-strided over 200 contiguous ints); rowdot gather
// hits L2 (400 KB table).
__global__ __launch_bounds__(256) void pool_kernel(const int* __restrict__ idx,
                                                   const float* __restrict__ rowdot,
                                                   float* __restrict__ out) {
    int wave = (blockIdx.x * blockDim.x + threadIdx.x) >> 6;
    int lane = threadIdx.x & 63;
    if (wave >= BB) return;
    const int* row = idx + (size_t)wave * LL;
    float s = 0.0f;
    #pragma unroll
    for (int t = lane; t < LL; t += 64)
        s += rowdot[row[t]];
    #pragma unroll
    for (int off = 32; off > 0; off >>= 1)
        s += __shfl_down(s, off, 64);
    if (lane == 0) out[wave] = s * (1.0f / LL);
}

// Fallback (ws too small): direct wave-per-b, dot computed on the fly.
__global__ __launch_bounds__(256) void direct_kernel(const int* __restrict__ idx,
                                                     const float* __restrict__ E,
                                                     const float* __restrict__ w,
                                                     float* __restrict__ out) {
    __shared__ float ws_sh[DD];
    for (int i = threadIdx.x; i < DD; i += blockDim.x) ws_sh[i] = w[i];
    __syncthreads();
    int wave = (blockIdx.x * blockDim.x + threadIdx.x) >> 6;
    int lane = threadIdx.x & 63;
    if (wave >= BB) return;
    const int* row = idx + (size_t)wave * LL;
    float s = 0.0f;
    for (int t = lane; t < LL; t += 64) {
        const float4* r = (const float4*)(E + (size_t)row[t] * DD);
        float acc = 0.0f;
        #pragma unroll
        for (int q = 0; q < DD / 4; ++q) {
            float4 v = r[q];
            acc += v.x * ws_sh[4 * q + 0] + v.y * ws_sh[4 * q + 1]
                 + v.z * ws_sh[4 * q + 2] + v.w * ws_sh[4 * q + 3];
        }
        s += acc;
    }
    #pragma unroll
    for (int off = 32; off > 0; off >>= 1)
        s += __shfl_down(s, off, 64);
    if (lane == 0) out[wave] = s * (1.0f / LL);
}

extern "C" void kernel_launch(void* const* d_in, const int* in_sizes, int n_in,
                              void* d_out, int out_size, void* d_ws, size_t ws_size,
                              hipStream_t stream) {
    const int*   word_idxs = (const int*)d_in[0];     // [B, L] int32
    const float* embed     = (const float*)d_in[1];   // [V, D] f32
    const float* weights   = (const float*)d_in[2];   // [D, 1] f32
    float*       out       = (float*)d_out;           // [B, 1] f32

    if (ws_size >= (size_t)VV * sizeof(float)) {
        float* rowdot = (float*)d_ws;
        // 100000 rows, 4 waves/block -> 25000 blocks exactly
        rowdot_kernel<<<(VV + 3) / 4, 256, 0, stream>>>(embed, weights, rowdot);
        // 16384 batch rows, 4 waves/block -> 4096 blocks exactly
        pool_kernel<<<BB / 4, 256, 0, stream>>>(word_idxs, rowdot, out);
    } else {
        direct_kernel<<<BB / 4, 256, 0, stream>>>(word_idxs, embed, weights, out);
    }
}

// Round 3
// 28.626 us; speedup vs baseline: 1.2784x; 1.2784x over previous
//
#include <hip/hip_runtime.h>

#define BB 16384
#define LL 200
#define DD 100
#define VV 100000

// Kernel 1: rowdot[v] = sum_d E[v,d] * w[d].
// Half-wave (32 lanes) per row; lanes 0..24 of each half load one float4
// (25 x 16B = 400B = one row). Weights held in one float4 register per lane.
// Per 64-lane wave: 2 rows, 800 B, a single global_load_dwordx4 instruction.
__global__ __launch_bounds__(256) void rowdot_kernel(const float4* __restrict__ E4,
                                                     const float4* __restrict__ w4,
                                                     float* __restrict__ rowdot) {
    const int tid     = blockIdx.x * blockDim.x + threadIdx.x;
    const int wave    = tid >> 6;          // global wave id
    const int lane    = threadIdx.x & 63;
    const int half    = lane >> 5;         // 0 or 1
    const int sublane = lane & 31;

    // weight fragment for this lane (same for both halves)
    float4 wv = make_float4(0.f, 0.f, 0.f, 0.f);
    if (sublane < 25) wv = w4[sublane];

    const int r = wave * 2 + half;         // row handled by this half-wave
    float s = 0.0f;
    if (sublane < 25) {
        float4 v = E4[(size_t)r * 25 + sublane];
        s = v.x * wv.x + v.y * wv.y + v.z * wv.z + v.w * wv.w;
    }
    // reduce within the 32-lane half (offsets 16..1 never cross the half)
    #pragma unroll
    for (int off = 16; off > 0; off >>= 1)
        s += __shfl_xor(s, off, 64);
    if (sublane == 0) rowdot[r] = s;
}

// Kernel 2: out[b] = (1/L) * sum_l rowdot[idx[b,l]].
// One wave per batch row. Lanes 0..49 load one int4 (50 x int4 = 200 idx),
// then do 4 independent gathers from the L2-resident 400 KB rowdot table.
__global__ __launch_bounds__(256) void pool_kernel(const int4* __restrict__ idx4,
                                                   const float* __restrict__ rowdot,
                                                   float* __restrict__ out) {
    const int tid  = blockIdx.x * blockDim.x + threadIdx.x;
    const int wave = tid >> 6;
    const int lane = threadIdx.x & 63;

    float s = 0.0f;
    if (lane < 50) {
        int4 i4 = idx4[(size_t)wave * 50 + lane];
        // 4 independent gathers -> memory-level parallelism
        float a = rowdot[i4.x];
        float b = rowdot[i4.y];
        float c = rowdot[i4.z];
        float d = rowdot[i4.w];
        s = (a + b) + (c + d);
    }
    #pragma unroll
    for (int off = 32; off > 0; off >>= 1)
        s += __shfl_xor(s, off, 64);
    if (lane == 0) out[wave] = s * (1.0f / LL);
}

extern "C" void kernel_launch(void* const* d_in, const int* in_sizes, int n_in,
                              void* d_out, int out_size, void* d_ws, size_t ws_size,
                              hipStream_t stream) {
    const int*   word_idxs = (const int*)d_in[0];     // [B, L] int32
    const float* embed     = (const float*)d_in[1];   // [V, D] f32
    const float* weights   = (const float*)d_in[2];   // [D, 1] f32
    float*       out       = (float*)d_out;           // [B, 1] f32
    float*       rowdot    = (float*)d_ws;            // 400 KB scratch

    // 100000 rows, 2 rows/wave, 4 waves/block -> 8 rows/block -> 12500 blocks
    rowdot_kernel<<<VV / 8, 256, 0, stream>>>((const float4*)embed,
                                              (const float4*)weights, rowdot);
    // 16384 batch rows, 1 row/wave, 4 waves/block -> 4096 blocks
    pool_kernel<<<BB / 4, 256, 0, stream>>>((const int4*)word_idxs, rowdot, out);
}